// Round 3
// baseline (136.669 us; speedup 1.0000x reference)
//
#include <hip/hip_runtime.h>
#include <hip/hip_bf16.h>
#include <cstdint>
#include <cstddef>

#define SCALE 0.42044820762685725f  // 32^(-1/4)

typedef __attribute__((ext_vector_type(8))) short short8;
typedef __attribute__((ext_vector_type(4))) float f32x4;

__device__ __forceinline__ unsigned int pk2bf(float lo, float hi) {
    __hip_bfloat162 h = __float22bfloat162_rn(float2{lo, hi});  // v_cvt_pk_bf16_f32
    unsigned int u;
    __builtin_memcpy(&u, &h, sizeof(u));
    return u;
}
__device__ __forceinline__ unsigned short f2bf(float f) {
    unsigned int u = __builtin_bit_cast(unsigned int, f);
    u = (u + 0x7fffu + ((u >> 16) & 1u)) >> 16;   // RNE
    return (unsigned short)u;
}
__device__ __forceinline__ float bf2f(unsigned short h) {
    unsigned int u = ((unsigned int)h) << 16;
    return __builtin_bit_cast(float, u);
}

// ---------------- prepack ----------------
// ws layout: [0, 262144) bytes: KV A-frags bf16, idx = ((mtg*8+ks)*64+lane)*8+j
//            <-> W[256 + mtg*16 + (lane&15)][ks*32 + (lane>>4)*8 + j]   (mtg 0..31)
// [262144, 327680) bytes: posT fp32 [k=64][o=256],  posT[k*256+o] = pos[o*64+k]
__global__ __launch_bounds__(256) void prepack_w(const float* __restrict__ w,
                                                 const float* __restrict__ pos,
                                                 unsigned short* __restrict__ wp,
                                                 float* __restrict__ pT) {
    int gid = blockIdx.x * 256 + threadIdx.x;
    if (gid < 16384) {
        int lane = gid & 63;
        int ks   = (gid >> 6) & 7;
        int mtg  = gid >> 9;
        int row  = 256 + mtg * 16 + (lane & 15);
        int k0   = ks * 32 + (lane >> 4) * 8;
        const float* src = w + row * 256 + k0;
        short8 v;
#pragma unroll
        for (int j = 0; j < 8; ++j) v[j] = (short)f2bf(src[j]);
        *reinterpret_cast<short8*>(wp + (size_t)gid * 8) = v;
    } else {
        int u = gid - 16384;              // k*256 + o
        pT[u] = pos[(u & 255) * 64 + (u >> 8)];
    }
}

// ---------------- main fused kernel: one WG per 8x8 tile, 4 waves ----------------
// Wave w owns: q rows [64w,64w+64), key rows [64w,64w+64), value rows [64w,64w+64),
// heads {2w, 2w+1}.  Only 2 barriers (after x-stage, after both GEMM passes).
template <bool PRE>
__global__ __launch_bounds__(256, 3) void attn_fused(
        const float* __restrict__ x, const float* __restrict__ proj_w,
        const float* __restrict__ proj_b, const float* __restrict__ pos,
        const unsigned short* __restrict__ wpack, const float* __restrict__ posT,
        float* __restrict__ out) {
    // s_main: union of x-tile (bf16 [p=64][c=256] swizzled, 32768B)
    //         and key-LDS  (bf16 [k=64][m=260] pad + XOR,   33280B)
    __shared__ __align__(16) unsigned char s_main[33280];
    __shared__ __align__(16) float s_xrow[256];   // x[:, p0] fp32
    __shared__ __align__(16) float s_qs[256];     // scale*(q + bias)
    __shared__ __align__(16) float s_attn[512];   // [head][k]
    __shared__ __align__(16) float s_vbias[256];

    const int t    = threadIdx.x;
    const int lane = t & 63;
    const int wave = t >> 6;
    const int l15  = lane & 15;
    const int l4   = lane >> 4;

    // XCD-chunked swizzle: XCD i gets tiles [i*256, i*256+256) = one full image
    int bid  = blockIdx.x;
    int tile = (bid & 7) * 256 + (bid >> 3);
    int b  = tile >> 8;
    int hq = (tile >> 4) & 15;
    int wq = tile & 15;
    int h0 = hq * 8, w0 = wq * 8;

    const float* xb = x + (size_t)b * 4194304 + (size_t)h0 * 128 + w0;

    s_vbias[t] = proj_b[512 + t];
    s_xrow[t]  = xb[(size_t)t * 16384];   // x[c=t][p0]

    // ---- stage x tile: gather 8 ch x 1 px -> one b128 write, [p][c] swizzled ----
    {
        const int p  = lane;
        const int px = (p >> 3) * 128 + (p & 7);
#pragma unroll
        for (int g = 0; g < 8; ++g) {
            const int c8 = g * 4 + wave;               // covers c8 = 0..31
            const float* src = xb + (size_t)(c8 * 8) * 16384 + px;
            float v[8];
#pragma unroll
            for (int j = 0; j < 8; ++j) v[j] = src[(size_t)j * 16384];
            uint4 pk;
            pk.x = pk2bf(v[0], v[1]); pk.y = pk2bf(v[2], v[3]);
            pk.z = pk2bf(v[4], v[5]); pk.w = pk2bf(v[6], v[7]);
            // quad = (c8 ^ (p&7)) & 7 -> 8 lanes per quad: b128 floor, no waste
            *reinterpret_cast<uint4*>(s_main + p * 512 + ((c8 * 16) ^ ((p & 7) << 4))) = pk;
        }
    }
    __syncthreads();

    // ---- Q matvec: thread t -> output o=t (wave-local rows). fp32, no converts ----
    {
        float qa[8] = {0.f,0.f,0.f,0.f,0.f,0.f,0.f,0.f};
        const float* wrow = proj_w + (size_t)t * 256;
#pragma unroll 8
        for (int c4 = 0; c4 < 64; ++c4) {
            float4 wv = *reinterpret_cast<const float4*>(wrow + c4 * 4);
            float4 xv = *reinterpret_cast<const float4*>(s_xrow + c4 * 4);
            float& a = qa[c4 & 7];
            a = fmaf(wv.x, xv.x, fmaf(wv.y, xv.y, fmaf(wv.z, xv.z, fmaf(wv.w, xv.w, a))));
        }
        float q = ((qa[0] + qa[1]) + (qa[2] + qa[3])) + ((qa[4] + qa[5]) + (qa[6] + qa[7]));
        s_qs[t] = SCALE * (q + proj_b[t]);
    }

    // ---- KV GEMM, two passes sharing one 64-reg accumulator ----
    f32x4 acc[4][4];
    auto kv_pass = [&](int mbase) {
#pragma unroll
        for (int mt = 0; mt < 4; ++mt)
#pragma unroll
            for (int nt = 0; nt < 4; ++nt) acc[mt][nt] = (f32x4){0.f, 0.f, 0.f, 0.f};
#pragma unroll 2
        for (int ks = 0; ks < 8; ++ks) {
            short8 bfr[4];
#pragma unroll
            for (int nt = 0; nt < 4; ++nt) {
                int n  = nt * 16 + l15;
                int kb = ks * 32 + l4 * 8;
                bfr[nt] = *reinterpret_cast<const short8*>(
                    s_main + n * 512 + ((2 * kb) ^ ((n & 7) << 4)));
            }
#pragma unroll
            for (int mt = 0; mt < 4; ++mt) {
                short8 afr;
                if (PRE) {
                    afr = *reinterpret_cast<const short8*>(
                        wpack + ((size_t)(((mbase + wave * 4 + mt) * 8 + ks) * 64 + lane)) * 8);
                } else {
                    int row = 256 + (mbase + wave * 4 + mt) * 16 + l15;
                    const float* wp2 = proj_w + row * 256 + ks * 32 + l4 * 8;
#pragma unroll
                    for (int j = 0; j < 8; ++j) afr[j] = (short)f2bf(wp2[j]);
                }
#pragma unroll
                for (int nt = 0; nt < 4; ++nt)
                    acc[mt][nt] = __builtin_amdgcn_mfma_f32_16x16x32_bf16(afr, bfr[nt], acc[mt][nt], 0, 0, 0);
            }
        }
    };

    kv_pass(0);                       // keys: qkv rows 256..511 (no bias: softmax-invariant)
    unsigned int kpk[4][4][2];        // keys packed bf16, 32 VGPRs
#pragma unroll
    for (int mt = 0; mt < 4; ++mt)
#pragma unroll
        for (int nt = 0; nt < 4; ++nt) {
            kpk[mt][nt][0] = pk2bf(acc[mt][nt][0], acc[mt][nt][1]);
            kpk[mt][nt][1] = pk2bf(acc[mt][nt][2], acc[mt][nt][3]);
        }
    kv_pass(16);                      // values: qkv rows 512..767 (stay in acc)

    __syncthreads();                  // all waves done reading x tile

    // ---- write own key rows to LDS [k=64][m=260], 8B-granular XOR on column ----
#pragma unroll
    for (int mt = 0; mt < 4; ++mt) {
        int m0 = wave * 64 + mt * 16 + l4 * 4;
#pragma unroll
        for (int nt = 0; nt < 4; ++nt) {
            int k = nt * 16 + l15;
            uint2 w2; w2.x = kpk[mt][nt][0]; w2.y = kpk[mt][nt][1];
            *reinterpret_cast<uint2*>(s_main + k * 520 + ((2 * m0) ^ (nt << 3))) = w2;
        }
    }
    // this wave reads only its own rows below -> no barrier (lgkmcnt ordering)

    // ---- softmax: heads 2w, 2w+1; lane = key index ----
    {
        const int k = lane;
        const int xv = ((k >> 4) & 3) << 3;
        const unsigned char* krow = s_main + k * 520;
        float lg0 = 0.f, lg1 = 0.f;
        if (PRE) {
            const float* pT = posT + (size_t)k * 256 + wave * 64;
#pragma unroll
            for (int d4 = 0; d4 < 8; ++d4) {
                f32x4 p0 = *reinterpret_cast<const f32x4*>(pT + d4 * 4);
                f32x4 p1 = *reinterpret_cast<const f32x4*>(pT + 32 + d4 * 4);
#pragma unroll
                for (int u = 0; u < 4; ++u) {
                    int o0 = wave * 64 + d4 * 4 + u;
                    float q0 = s_qs[o0], q1 = s_qs[o0 + 32];
                    float v0 = bf2f(*reinterpret_cast<const unsigned short*>(krow + ((2 * o0) ^ xv)));
                    float v1 = bf2f(*reinterpret_cast<const unsigned short*>(krow + ((2 * (o0 + 32)) ^ xv)));
                    lg0 = fmaf(q0, fmaf(SCALE, v0, p0[u]), lg0);
                    lg1 = fmaf(q1, fmaf(SCALE, v1, p1[u]), lg1);
                }
            }
        } else {
#pragma unroll 4
            for (int d = 0; d < 32; ++d) {
                int o0 = wave * 64 + d;
                float q0 = s_qs[o0], q1 = s_qs[o0 + 32];
                float p0 = pos[o0 * 64 + k], p1 = pos[(o0 + 32) * 64 + k];
                float v0 = bf2f(*reinterpret_cast<const unsigned short*>(krow + ((2 * o0) ^ xv)));
                float v1 = bf2f(*reinterpret_cast<const unsigned short*>(krow + ((2 * (o0 + 32)) ^ xv)));
                lg0 = fmaf(q0, fmaf(SCALE, v0, p0), lg0);
                lg1 = fmaf(q1, fmaf(SCALE, v1, p1), lg1);
            }
        }
        float m0v = lg0, m1v = lg1;
#pragma unroll
        for (int off = 32; off >= 1; off >>= 1) {
            m0v = fmaxf(m0v, __shfl_xor(m0v, off));
            m1v = fmaxf(m1v, __shfl_xor(m1v, off));
        }
        float e0 = __expf(lg0 - m0v), e1 = __expf(lg1 - m1v);
        float s0 = e0, s1 = e1;
#pragma unroll
        for (int off = 32; off >= 1; off >>= 1) {
            s0 += __shfl_xor(s0, off);
            s1 += __shfl_xor(s1, off);
        }
        s_attn[(2 * wave) * 64 + k]     = e0 / s0;
        s_attn[(2 * wave + 1) * 64 + k] = e1 / s1;
    }
    // same-wave RAW on s_attn -> no barrier

    // ---- epilogue: out = attn @ values from own acc; Σattn=1 folds value bias ----
#pragma unroll
    for (int mt = 0; mt < 4; ++mt) {
        int head = 2 * wave + (mt >> 1);
        const float* ap = s_attn + head * 64;
        float a0 = ap[l15], a1 = ap[16 + l15], a2 = ap[32 + l15], a3 = ap[48 + l15];
#pragma unroll
        for (int i = 0; i < 4; ++i) {
            float sum = a0 * acc[mt][0][i] + a1 * acc[mt][1][i]
                      + a2 * acc[mt][2][i] + a3 * acc[mt][3][i];
            sum += __shfl_xor(sum, 1);
            sum += __shfl_xor(sum, 2);
            sum += __shfl_xor(sum, 4);
            sum += __shfl_xor(sum, 8);
            if (l15 == 0) {
                int vr = wave * 64 + mt * 16 + l4 * 4 + i;
                out[(size_t)b * 65536 + (size_t)vr * 256 + hq * 16 + wq] = sum + s_vbias[vr];
            }
        }
    }
}

extern "C" void kernel_launch(void* const* d_in, const int* in_sizes, int n_in,
                              void* d_out, int out_size, void* d_ws, size_t ws_size,
                              hipStream_t stream) {
    (void)in_sizes; (void)n_in; (void)out_size;
    const float* x      = (const float*)d_in[0];
    const float* proj_w = (const float*)d_in[1];
    const float* proj_b = (const float*)d_in[2];
    const float* pos    = (const float*)d_in[3];
    float* out = (float*)d_out;

    const size_t need_ws = 262144 + 65536;   // KV A-frags bf16 + posT f32
    if (d_ws != nullptr && ws_size >= need_ws) {
        unsigned short* wp = (unsigned short*)d_ws;
        float* pT = (float*)((char*)d_ws + 262144);
        prepack_w<<<128, 256, 0, stream>>>(proj_w, pos, wp, pT);
        attn_fused<true><<<2048, 256, 0, stream>>>(x, proj_w, proj_b, pos, wp, pT, out);
    } else {
        attn_fused<false><<<2048, 256, 0, stream>>>(x, proj_w, proj_b, pos, nullptr, nullptr, out);
    }
}

// Round 4
// 116.548 us; speedup vs baseline: 1.1726x; 1.1726x over previous
//
#include <hip/hip_runtime.h>
#include <hip/hip_bf16.h>
#include <cstdint>
#include <cstddef>

#define SCALE 0.42044820762685725f  // 32^(-1/4)

typedef __attribute__((ext_vector_type(8))) short short8;
typedef __attribute__((ext_vector_type(4))) float f32x4;

__device__ __forceinline__ unsigned int pk2bf(float lo, float hi) {
    __hip_bfloat162 h = __float22bfloat162_rn(float2{lo, hi});  // v_cvt_pk_bf16_f32
    unsigned int u;
    __builtin_memcpy(&u, &h, sizeof(u));
    return u;
}
__device__ __forceinline__ unsigned short f2bf(float f) {
    unsigned int u = __builtin_bit_cast(unsigned int, f);
    u = (u + 0x7fffu + ((u >> 16) & 1u)) >> 16;   // RNE
    return (unsigned short)u;
}
__device__ __forceinline__ float bf2f(unsigned short h) {
    unsigned int u = ((unsigned int)h) << 16;
    return __builtin_bit_cast(float, u);
}

// ---------------- prepack: W -> bf16 MFMA A-frags ----------------
// mtg 0..31  : KV rows 256 + mtg*16 ..        (keys 256..511, values 512..767)
// mtg 32..47 : Q  rows (mtg-32)*16 ..          (q 0..255)
// idx = ((mtg*8 + ks)*64 + lane)*8 + j  <->  W[row(mtg) + (lane&15)][ks*32 + (lane>>4)*8 + j]
__global__ __launch_bounds__(256) void prepack_w(const float* __restrict__ w,
                                                 unsigned short* __restrict__ wp) {
    int gid  = blockIdx.x * 256 + threadIdx.x;   // < 24576
    int lane = gid & 63;
    int ks   = (gid >> 6) & 7;
    int mtg  = gid >> 9;                          // 0..47
    int row  = (mtg < 32 ? 256 + mtg * 16 : (mtg - 32) * 16) + (lane & 15);
    int k0   = ks * 32 + (lane >> 4) * 8;
    const float* src = w + row * 256 + k0;
    short8 v;
#pragma unroll
    for (int j = 0; j < 8; ++j) v[j] = (short)f2bf(src[j]);
    *reinterpret_cast<short8*>(wp + (size_t)gid * 8) = v;
}

// ---------------- main fused kernel: one WG per 8x8 tile, 4 waves ----------------
// Wave w owns: q rows [64w,64w+64), key rows [64w,64w+64), value rows [64w,64w+64),
// heads {2w, 2w+1}.  2 barriers total.
template <bool PRE>
__global__ __launch_bounds__(256, 2) void attn_fused(
        const float* __restrict__ x, const float* __restrict__ proj_w,
        const float* __restrict__ proj_b, const float* __restrict__ pos,
        const unsigned short* __restrict__ wpack, float* __restrict__ out) {
    // s_main: union of x-tile (bf16 [p=64][c=256] swizzled, 32768B)
    //         and key-LDS  (bf16 [k=64][m=260] pad + XOR,   33280B)
    __shared__ __align__(16) unsigned char s_main[33280];
    __shared__ __align__(16) float s_qs[256];     // scale*(q + bias)
    __shared__ __align__(16) float s_attn[512];   // [head][k]
    __shared__ __align__(16) float s_vbias[256];

    const int t    = threadIdx.x;
    const int lane = t & 63;
    const int wave = t >> 6;
    const int l15  = lane & 15;
    const int l4   = lane >> 4;

    // XCD-chunked swizzle: XCD i gets tiles [i*256, i*256+256) = one full image
    int bid  = blockIdx.x;
    int tile = (bid & 7) * 256 + (bid >> 3);
    int b  = tile >> 8;
    int hq = (tile >> 4) & 15;
    int wq = tile & 15;
    int h0 = hq * 8, w0 = wq * 8;

    const float* xb = x + (size_t)b * 4194304 + (size_t)h0 * 128 + w0;

    s_vbias[t] = proj_b[512 + t];

    // ---- stage x tile -> bf16 [p][c] swizzled LDS ----
    // lane-pair float2 loads (64B segments) + one shfl to transpose 2px*1c -> 1px*2c
    {
        const int p   = lane;
        const int pl  = lane & 1;
        const int px0 = lane & ~1;
        const float* xpx = xb + (px0 >> 3) * 128 + (px0 & 7);
#pragma unroll
        for (int h = 0; h < 8; ++h) {
            const int C0 = h * 32 + wave * 8;
            uint4 pk;
            unsigned int* pku = &pk.x;
#pragma unroll
            for (int j = 0; j < 4; ++j) {
                int c = C0 + 2 * j + pl;
                float2 v = *reinterpret_cast<const float2*>(xpx + (size_t)c * 16384);
                float sel   = pl ? v.x : v.y;
                float other = __shfl_xor(sel, 1);
                pku[j] = pl ? pk2bf(other, v.y) : pk2bf(v.x, other);
            }
            const int c8 = h * 4 + wave;
            *reinterpret_cast<uint4*>(s_main + p * 512 + ((c8 * 16) ^ ((p & 7) << 4))) = pk;
        }
    }
    __syncthreads();

    // ---- pass 1: keys (rows 256..511) + q (rows 0..255, B-cols 0..15 only) ----
    f32x4 acc[4][4];
    f32x4 accQ[4];
#pragma unroll
    for (int mt = 0; mt < 4; ++mt) {
        accQ[mt] = (f32x4){0.f, 0.f, 0.f, 0.f};
#pragma unroll
        for (int nt = 0; nt < 4; ++nt) acc[mt][nt] = (f32x4){0.f, 0.f, 0.f, 0.f};
    }

#pragma unroll 2
    for (int ks = 0; ks < 8; ++ks) {
        short8 bfr[4];
#pragma unroll
        for (int nt = 0; nt < 4; ++nt) {
            int n  = nt * 16 + l15;
            int kb = ks * 32 + l4 * 8;
            bfr[nt] = *reinterpret_cast<const short8*>(
                s_main + n * 512 + ((2 * kb) ^ ((n & 7) << 4)));
        }
        short8 afk[4], afq[4];
#pragma unroll
        for (int mt = 0; mt < 4; ++mt) {
            if (PRE) {
                afk[mt] = *reinterpret_cast<const short8*>(
                    wpack + ((size_t)(((wave * 4 + mt) * 8 + ks) * 64 + lane)) * 8);
                afq[mt] = *reinterpret_cast<const short8*>(
                    wpack + ((size_t)(((32 + wave * 4 + mt) * 8 + ks) * 64 + lane)) * 8);
            } else {
                const float* wk = proj_w + (256 + (wave * 4 + mt) * 16 + l15) * 256 + ks * 32 + l4 * 8;
                const float* wq2 = proj_w + ((wave * 4 + mt) * 16 + l15) * 256 + ks * 32 + l4 * 8;
#pragma unroll
                for (int j = 0; j < 8; ++j) { afk[mt][j] = (short)f2bf(wk[j]); afq[mt][j] = (short)f2bf(wq2[j]); }
            }
        }
#pragma unroll
        for (int mt = 0; mt < 4; ++mt)
#pragma unroll
            for (int nt = 0; nt < 4; ++nt)
                acc[mt][nt] = __builtin_amdgcn_mfma_f32_16x16x32_bf16(afk[mt], bfr[nt], acc[mt][nt], 0, 0, 0);
#pragma unroll
        for (int mt = 0; mt < 4; ++mt)
            accQ[mt] = __builtin_amdgcn_mfma_f32_16x16x32_bf16(afq[mt], bfr[0], accQ[mt], 0, 0, 0);
    }

    // q: C-frag col = l15; pixel 0 = col 0
    if (l15 == 0) {
#pragma unroll
        for (int mt = 0; mt < 4; ++mt)
#pragma unroll
            for (int i = 0; i < 4; ++i) {
                int row = wave * 64 + mt * 16 + l4 * 4 + i;
                s_qs[row] = SCALE * (accQ[mt][i] + proj_b[row]);
            }
    }

    // pack keys to bf16 (no key bias: softmax shift-invariant)
    unsigned int kpk[4][4][2];
#pragma unroll
    for (int mt = 0; mt < 4; ++mt)
#pragma unroll
        for (int nt = 0; nt < 4; ++nt) {
            kpk[mt][nt][0] = pk2bf(acc[mt][nt][0], acc[mt][nt][1]);
            kpk[mt][nt][1] = pk2bf(acc[mt][nt][2], acc[mt][nt][3]);
        }

    // ---- pass 2: values (rows 512..767), reuse acc ----
#pragma unroll
    for (int mt = 0; mt < 4; ++mt)
#pragma unroll
        for (int nt = 0; nt < 4; ++nt) acc[mt][nt] = (f32x4){0.f, 0.f, 0.f, 0.f};
#pragma unroll 2
    for (int ks = 0; ks < 8; ++ks) {
        short8 bfr[4];
#pragma unroll
        for (int nt = 0; nt < 4; ++nt) {
            int n  = nt * 16 + l15;
            int kb = ks * 32 + l4 * 8;
            bfr[nt] = *reinterpret_cast<const short8*>(
                s_main + n * 512 + ((2 * kb) ^ ((n & 7) << 4)));
        }
        short8 afv[4];
#pragma unroll
        for (int mt = 0; mt < 4; ++mt) {
            if (PRE) {
                afv[mt] = *reinterpret_cast<const short8*>(
                    wpack + ((size_t)(((16 + wave * 4 + mt) * 8 + ks) * 64 + lane)) * 8);
            } else {
                const float* wv = proj_w + (512 + (wave * 4 + mt) * 16 + l15) * 256 + ks * 32 + l4 * 8;
#pragma unroll
                for (int j = 0; j < 8; ++j) afv[mt][j] = (short)f2bf(wv[j]);
            }
        }
#pragma unroll
        for (int mt = 0; mt < 4; ++mt)
#pragma unroll
            for (int nt = 0; nt < 4; ++nt)
                acc[mt][nt] = __builtin_amdgcn_mfma_f32_16x16x32_bf16(afv[mt], bfr[nt], acc[mt][nt], 0, 0, 0);
    }

    __syncthreads();   // all waves done reading x tile; s_main becomes key-LDS

    // ---- write own key rows to LDS [k=64][m=260], 8B-granular XOR on column ----
#pragma unroll
    for (int mt = 0; mt < 4; ++mt) {
        int m0 = wave * 64 + mt * 16 + l4 * 4;
#pragma unroll
        for (int nt = 0; nt < 4; ++nt) {
            int k = nt * 16 + l15;
            uint2 w2; w2.x = kpk[mt][nt][0]; w2.y = kpk[mt][nt][1];
            *reinterpret_cast<uint2*>(s_main + k * 520 + ((2 * m0) ^ (nt << 3))) = w2;
        }
    }
    // wave reads only its own rows below -> no barrier (compiler lgkmcnt ordering)

    // ---- softmax: heads 2w, 2w+1; lane = key index; pos reads coalesced ----
    {
        const int k  = lane;
        const int xv = ((k >> 4) & 3) << 3;
        const unsigned char* krow = s_main + k * 520;
        float lg0 = 0.f, lg1 = 0.f;
#pragma unroll 8
        for (int d = 0; d < 32; ++d) {
            int o0 = wave * 64 + d, o1 = o0 + 32;
            float q0 = s_qs[o0], q1 = s_qs[o1];
            float p0 = pos[o0 * 64 + k], p1 = pos[o1 * 64 + k];
            float v0 = bf2f(*reinterpret_cast<const unsigned short*>(krow + ((2 * o0) ^ xv)));
            float v1 = bf2f(*reinterpret_cast<const unsigned short*>(krow + ((2 * o1) ^ xv)));
            lg0 = fmaf(q0, fmaf(SCALE, v0, p0), lg0);
            lg1 = fmaf(q1, fmaf(SCALE, v1, p1), lg1);
        }
        float m0v = lg0, m1v = lg1;
#pragma unroll
        for (int off = 32; off >= 1; off >>= 1) {
            m0v = fmaxf(m0v, __shfl_xor(m0v, off));
            m1v = fmaxf(m1v, __shfl_xor(m1v, off));
        }
        float e0 = __expf(lg0 - m0v), e1 = __expf(lg1 - m1v);
        float s0 = e0, s1 = e1;
#pragma unroll
        for (int off = 32; off >= 1; off >>= 1) {
            s0 += __shfl_xor(s0, off);
            s1 += __shfl_xor(s1, off);
        }
        s_attn[(2 * wave) * 64 + k]     = e0 / s0;
        s_attn[(2 * wave + 1) * 64 + k] = e1 / s1;
    }
    // same-wave RAW on s_attn -> no barrier

    // ---- epilogue: out = attn @ values from own acc; Σattn=1 folds value bias ----
#pragma unroll
    for (int mt = 0; mt < 4; ++mt) {
        int head = 2 * wave + (mt >> 1);
        const float* ap = s_attn + head * 64;
        float a0 = ap[l15], a1 = ap[16 + l15], a2 = ap[32 + l15], a3 = ap[48 + l15];
#pragma unroll
        for (int i = 0; i < 4; ++i) {
            float sum = a0 * acc[mt][0][i] + a1 * acc[mt][1][i]
                      + a2 * acc[mt][2][i] + a3 * acc[mt][3][i];
            sum += __shfl_xor(sum, 1);
            sum += __shfl_xor(sum, 2);
            sum += __shfl_xor(sum, 4);
            sum += __shfl_xor(sum, 8);
            if (l15 == 0) {
                int vr = wave * 64 + mt * 16 + l4 * 4 + i;
                out[(size_t)b * 65536 + (size_t)vr * 256 + hq * 16 + wq] = sum + s_vbias[vr];
            }
        }
    }
}

extern "C" void kernel_launch(void* const* d_in, const int* in_sizes, int n_in,
                              void* d_out, int out_size, void* d_ws, size_t ws_size,
                              hipStream_t stream) {
    (void)in_sizes; (void)n_in; (void)out_size;
    const float* x      = (const float*)d_in[0];
    const float* proj_w = (const float*)d_in[1];
    const float* proj_b = (const float*)d_in[2];
    const float* pos    = (const float*)d_in[3];
    float* out = (float*)d_out;

    const size_t need_ws = 24576ull * 8 * sizeof(unsigned short);  // 384 KiB
    if (d_ws != nullptr && ws_size >= need_ws) {
        unsigned short* wp = (unsigned short*)d_ws;
        prepack_w<<<96, 256, 0, stream>>>(proj_w, wp);
        attn_fused<true><<<2048, 256, 0, stream>>>(x, proj_w, proj_b, pos, wp, out);
    } else {
        attn_fused<false><<<2048, 256, 0, stream>>>(x, proj_w, proj_b, pos, nullptr, out);
    }
}